// Round 9
// baseline (639.459 us; speedup 1.0000x reference)
//
#include <hip/hip_runtime.h>
#include <hip/hip_bf16.h>

typedef __hip_bfloat16 bf16;
typedef __attribute__((ext_vector_type(8))) short short8;   // 8 bf16 (4 VGPRs)
typedef __attribute__((ext_vector_type(4))) float f32x4;    // 4 fp32 acc
typedef __attribute__((ext_vector_type(2))) float f32x2;

constexpr int NN = 50000;   // nodes
constexpr int NE = 800000;  // edges
constexpr int IC = 64;      // in channels
constexpr int OC = 128;     // out channels
constexpr int NH = 4;       // heads
constexpr int RED_BLOCKS = 512;
constexpr unsigned F32_ONE = 0x3F800000u;

__device__ __forceinline__ float b2f(bf16 v) { return __bfloat162float(v); }

__device__ __forceinline__ float ldf(const void* p, int i, bool f32) {
    return f32 ? ((const float*)p)[i]
               : __bfloat162float(((const bf16*)p)[i]);
}

__device__ __forceinline__ int ld_idx(const void* p, long long i, bool i64) {
    return i64 ? (int)((const long long*)p)[i] : ((const int*)p)[i];
}

// f32 -> bf16 bits (RNE)
__device__ __forceinline__ unsigned f2bu(float x) {
    unsigned u = __float_as_uint(x);
    return (u + 0x7FFFu + ((u >> 16) & 1u)) >> 16;
}

// ---- fp8 e4m3 helpers (HW path with manual fallback) ----------------------
__device__ __forceinline__ unsigned char f32_to_fp8(float x) {
#if __has_builtin(__builtin_amdgcn_cvt_pk_fp8_f32)
    return (unsigned char)(__builtin_amdgcn_cvt_pk_fp8_f32(x, x, 0, false) & 0xFF);
#else
    unsigned bits = __float_as_uint(x);
    unsigned s = bits >> 31;
    float a = fabsf(x);
    if (a >= 448.f) return (unsigned char)((s << 7) | 0x7E);
    if (a < 0.015625f) {
        int m = (int)(a * 512.f + 0.5f);
        if (m >= 8) return (unsigned char)((s << 7) | 0x08);
        return (unsigned char)((s << 7) | m);
    }
    unsigned ab = (bits & 0x7FFFFFFFu) + 0x00080000u;
    int e8 = (int)(ab >> 23) - 127 + 7;
    unsigned m3 = (ab >> 20) & 7u;
    if (e8 >= 16) return (unsigned char)((s << 7) | 0x7E);
    return (unsigned char)((s << 7) | ((unsigned)e8 << 3) | m3);
#endif
}

__device__ __forceinline__ void fp8x4_to_f32(unsigned u, float& f0, float& f1,
                                             float& f2, float& f3) {
#if __has_builtin(__builtin_amdgcn_cvt_pk_f32_fp8)
    f32x2 lo = __builtin_amdgcn_cvt_pk_f32_fp8(u, false);
    f32x2 hi = __builtin_amdgcn_cvt_pk_f32_fp8(u, true);
    f0 = lo[0]; f1 = lo[1]; f2 = hi[0]; f3 = hi[1];
#else
    float r[4];
#pragma unroll
    for (int j = 0; j < 4; ++j) {
        unsigned b = (u >> (8 * j)) & 0xFF;
        unsigned s = b >> 7, e = (b >> 3) & 15, m = b & 7;
        float v = (e == 0) ? (float)m * 0.001953125f
                           : __uint_as_float(((e + 120u) << 23) | (m << 20));
        r[j] = s ? -v : v;
    }
    f0 = r[0]; f1 = r[1]; f2 = r[2]; f3 = r[3];
#endif
}

__device__ __forceinline__ void fp8x2_to_f32(unsigned u, float& f0, float& f1) {
#if __has_builtin(__builtin_amdgcn_cvt_pk_f32_fp8)
    f32x2 lo = __builtin_amdgcn_cvt_pk_f32_fp8(u, false);
    f0 = lo[0]; f1 = lo[1];
#else
    float r[2];
#pragma unroll
    for (int j = 0; j < 2; ++j) {
        unsigned b = (u >> (8 * j)) & 0xFF;
        unsigned s = b >> 7, e = (b >> 3) & 15, m = b & 7;
        float v = (e == 0) ? (float)m * 0.001953125f
                           : __uint_as_float(((e + 120u) << 23) | (m << 20));
        r[j] = s ? -v : v;
    }
    f0 = r[0]; f1 = r[1];
#endif
}

// online-softmax combine: (m,s) <- (m,s) + (m2,s2)
__device__ __forceinline__ void osm_comb(float& m, float& s, float m2, float s2) {
    float M = fmaxf(m, m2);
    s = s * __expf(m - M) + s2 * __expf(m2 - M);
    m = M;
}

// ---------------------------------------------------------------------------
// Kernel 0: probe edge_index width (int64 has zero high words).
// ---------------------------------------------------------------------------
__global__ void probe_idx(const unsigned* __restrict__ ei, unsigned* __restrict__ flags)
{
    if (threadIdx.x == 0 && blockIdx.x == 0) {
        bool i64 = true;
        for (int i = 0; i < 32; ++i) i64 = i64 && (ei[2 * i + 1] == 0u);
        flags[0] = i64 ? 1u : 0u;
    }
}

// ---------------------------------------------------------------------------
// Kernel 0b: tiny tables -> f32 (gate tables + fused projection bias bcat)
// ---------------------------------------------------------------------------
__global__ void cvt_small(const void* __restrict__ be1, const void* __restrict__ We2,
                          const void* __restrict__ be2, const unsigned* __restrict__ gw,
                          const void* __restrict__ bq, const void* __restrict__ bk,
                          const void* __restrict__ bv,
                          float* __restrict__ be1f, float* __restrict__ We2f,
                          float* __restrict__ be2f, float* __restrict__ bcat)
{
    const bool f32 = (gw[0] == F32_ONE);
    int t = threadIdx.x; // 256 threads
    if (t < OC) be1f[t] = ldf(be1, t, f32);
    for (int i = t; i < OC * NH; i += 256) We2f[i] = ldf(We2, i, f32);
    if (t < NH) be2f[t] = ldf(be2, t, f32);
    for (int n = t; n < 5 * OC; n += 256) {
        int sel = n >> 7, c = n & 127;
        float b = 0.f;
        if (sel == 0) b = ldf(bq, c, f32);
        else if (sel == 1) b = ldf(bk, c, f32);
        else if (sel == 2) b = ldf(bv, c, f32);
        bcat[n] = b;
    }
}

// ---------------------------------------------------------------------------
// Kernel 0c: x -> bf16 (xb aliased over logits; dead before edge_kernel)
// ---------------------------------------------------------------------------
__global__ __launch_bounds__(256) void cvt_x(const void* __restrict__ x,
                                             const unsigned* __restrict__ gw,
                                             bf16* __restrict__ xb)
{
    const bool f32 = (gw[0] == F32_ONE);
    int i = blockIdx.x * 256 + threadIdx.x;
    if (i < NN * IC) xb[i] = __float2bfloat16(ldf(x, i, f32));
}

// ---------------------------------------------------------------------------
// Kernel 0d: WcatT[640 x 64] bf16 (n-major, k contiguous)
// ---------------------------------------------------------------------------
__global__ __launch_bounds__(256) void cvt_w(const void* __restrict__ Wq,
                                             const void* __restrict__ Wk,
                                             const void* __restrict__ Wv,
                                             const void* __restrict__ We1,
                                             const unsigned* __restrict__ gw,
                                             bf16* __restrict__ WcatT)
{
    const bool f32 = (gw[0] == F32_ONE);
    int idx = blockIdx.x * 256 + threadIdx.x;   // n*64 + k
    if (idx >= 5 * OC * IC) return;
    int n = idx >> 6, k = idx & 63;
    int sel = n >> 7, c = n & 127;
    float v;
    if (sel == 0)      v = ldf(Wq, k * OC + c, f32);
    else if (sel == 1) v = ldf(Wk, k * OC + c, f32);
    else if (sel == 2) v = ldf(Wv, k * OC + c, f32);
    else if (sel == 3) v = ldf(We1, k * OC + c, f32);
    else               v = ldf(We1, (IC + k) * OC + c, f32);
    WcatT[idx] = __float2bfloat16(v);
}

// ---------------------------------------------------------------------------
// Kernel 0e: WoT[128 x 128] bf16 (n-major, k contiguous)
// ---------------------------------------------------------------------------
__global__ __launch_bounds__(256) void cvt_wo(const void* __restrict__ Wo,
                                              const unsigned* __restrict__ gw,
                                              bf16* __restrict__ WoT)
{
    const bool f32 = (gw[0] == F32_ONE);
    int idx = blockIdx.x * 256 + threadIdx.x;   // n*128 + k
    if (idx >= OC * OC) return;
    int n = idx >> 7, k = idx & 127;
    WoT[idx] = __float2bfloat16(ldf(Wo, k * OC + n, f32));
}

// ---------------------------------------------------------------------------
// Kernel 1: MFMA node projection GEMM. D[50000 x 640] = xb @ Wcat + bcat
// Outputs packed by index-affinity (fp8):
//   qb_dst[node]: 256 B row, chunks [q(4B) | b(4B)] x 32   (q=Wq, b=We1-bot)
//   ka_src[node]: 256 B row, chunks [k(4B) | a(4B)] x 32   (k=Wk, a=We1-top)
//   vf8[node]:    128 B row (v fp8)
// ---------------------------------------------------------------------------
__global__ __launch_bounds__(256) void node_gemm(
    const bf16* __restrict__ xb, const bf16* __restrict__ WcatT,
    const float* __restrict__ bcat,
    unsigned char* __restrict__ qb_dst, unsigned char* __restrict__ ka_src,
    unsigned char* __restrict__ vf8)
{
    int wave = threadIdx.x >> 6;
    int lane = threadIdx.x & 63;
    int quad = lane >> 4;
    int l16  = lane & 15;
    int row_base = blockIdx.x * 16;
    int m = row_base + l16;

    short8 a0 = *(const short8*)(xb + (size_t)m * IC + quad * 8);
    short8 a1 = *(const short8*)(xb + (size_t)m * IC + 32 + quad * 8);

#pragma unroll
    for (int t = 0; t < 10; ++t) {
        int colbase = wave * 160 + t * 16;
        const bf16* bp = WcatT + (size_t)(colbase + l16) * IC + quad * 8;
        short8 b0 = *(const short8*)(bp);
        short8 b1 = *(const short8*)(bp + 32);
        f32x4 acc = {0.f, 0.f, 0.f, 0.f};
        acc = __builtin_amdgcn_mfma_f32_16x16x32_bf16(a0, b0, acc, 0, 0, 0);
        acc = __builtin_amdgcn_mfma_f32_16x16x32_bf16(a1, b1, acc, 0, 0, 0);

        float bias = bcat[colbase + l16];
        int sel = colbase >> 7;              // uniform per tile
        int cc  = (colbase & 127) + l16;
        int chunk_off = (cc >> 2) * 8 + (cc & 3);
#pragma unroll
        for (int r = 0; r < 4; ++r) {
            int node = row_base + quad * 4 + r;
            unsigned char val = f32_to_fp8(acc[r] + bias);
            if (sel == 0)      qb_dst[(size_t)node * 256 + chunk_off] = val;
            else if (sel == 1) ka_src[(size_t)node * 256 + chunk_off] = val;
            else if (sel == 2) vf8[(size_t)node * OC + cc] = val;
            else if (sel == 3) ka_src[(size_t)node * 256 + chunk_off + 4] = val;
            else               qb_dst[(size_t)node * 256 + chunk_off + 4] = val;
        }
    }
}

// ---------------------------------------------------------------------------
// Kernel 2: per-edge gate + attention logit. Packed fp8 tables: 2 gathers/edge.
// One wave = 2 edges (32 lanes each, 4 channels per lane), no barriers.
// ---------------------------------------------------------------------------
__global__ __launch_bounds__(256) void edge_kernel(
    const void* __restrict__ eia, const void* __restrict__ eib, int split,
    const unsigned* __restrict__ flags,
    const unsigned char* __restrict__ qb_dst, const unsigned char* __restrict__ ka_src,
    const float* __restrict__ be1f, const float* __restrict__ We2f,
    const float* __restrict__ be2f,
    float* __restrict__ logits)
{
    const bool i64 = (flags[0] != 0u);
    int lane = threadIdx.x & 63;
    int wid  = threadIdx.x >> 6;
    int sub  = lane >> 5;
    int i    = lane & 31;
    int c    = i << 2;
    long long e = (long long)blockIdx.x * 8 + wid * 2 + sub;

    int s = ld_idx(eia, e, i64);
    int d = split ? ld_idx(eib, e, i64) : ld_idx(eia, NE + e, i64);

    uint2 ud = ((const uint2*)(qb_dst + (size_t)d * 256))[i];  // .x=q, .y=b
    uint2 us = ((const uint2*)(ka_src + (size_t)s * 256))[i];  // .x=k, .y=a
    float4 vb1 = *(const float4*)(be1f + c);
    float4 w0 = *(const float4*)(We2f + 4 * c);
    float4 w1 = *(const float4*)(We2f + 4 * (c + 1));
    float4 w2 = *(const float4*)(We2f + 4 * (c + 2));
    float4 w3 = *(const float4*)(We2f + 4 * (c + 3));

    float q0,q1,q2,q3, k0,k1,k2,k3, a0,a1,a2,a3, b0,b1,b2,b3;
    fp8x4_to_f32(ud.x, q0,q1,q2,q3);
    fp8x4_to_f32(ud.y, b0,b1,b2,b3);
    fp8x4_to_f32(us.x, k0,k1,k2,k3);
    fp8x4_to_f32(us.y, a0,a1,a2,a3);

    float t = q0*k0 + q1*k1 + q2*k2 + q3*k3;
    t += __shfl_xor(t, 1);
    t += __shfl_xor(t, 2);
    t += __shfl_xor(t, 4);

    float h0 = fmaxf(a0 + b0 + vb1.x, 0.f);
    float h1 = fmaxf(a1 + b1 + vb1.y, 0.f);
    float h2 = fmaxf(a2 + b2 + vb1.z, 0.f);
    float h3 = fmaxf(a3 + b3 + vb1.w, 0.f);
    float p0 = h0*w0.x + h1*w1.x + h2*w2.x + h3*w3.x;
    float p1 = h0*w0.y + h1*w1.y + h2*w2.y + h3*w3.y;
    float p2 = h0*w0.z + h1*w1.z + h2*w2.z + h3*w3.z;
    float p3 = h0*w0.w + h1*w1.w + h2*w2.w + h3*w3.w;
#pragma unroll
    for (int off = 1; off <= 16; off <<= 1) {
        p0 += __shfl_xor(p0, off);
        p1 += __shfl_xor(p1, off);
        p2 += __shfl_xor(p2, off);
        p3 += __shfl_xor(p3, off);
    }

    if ((i & 7) == 0) {
        int j = i >> 3;
        float pj = (j == 0) ? p0 : (j == 1) ? p1 : (j == 2) ? p2 : p3;
        float w = pj + be2f[j];
        logits[e * NH + j] = t * w * 0.17677669529663687f; // 1/sqrt(32)
    }
}

// ---------------------------------------------------------------------------
// Fused online-softmax stats: one pass over logits.
// part[b*8 + h] = m_b(h), part[b*8 + 4 + h] = s_b(h)
// ---------------------------------------------------------------------------
__global__ __launch_bounds__(256) void stat_part(const float* __restrict__ logits,
                                                 float* __restrict__ part)
{
    float m0=-1e30f,m1=-1e30f,m2=-1e30f,m3=-1e30f;
    float s0=0.f,s1=0.f,s2=0.f,s3=0.f;
    for (int e = blockIdx.x * 256 + threadIdx.x; e < NE; e += RED_BLOCKS * 256) {
        float4 l = reinterpret_cast<const float4*>(logits)[e];
        float M;
        M = fmaxf(m0, l.x); s0 = s0 * __expf(m0 - M) + __expf(l.x - M); m0 = M;
        M = fmaxf(m1, l.y); s1 = s1 * __expf(m1 - M) + __expf(l.y - M); m1 = M;
        M = fmaxf(m2, l.z); s2 = s2 * __expf(m2 - M) + __expf(l.z - M); m2 = M;
        M = fmaxf(m3, l.w); s3 = s3 * __expf(m3 - M) + __expf(l.w - M); m3 = M;
    }
#pragma unroll
    for (int off = 32; off >= 1; off >>= 1) {
        osm_comb(m0, s0, __shfl_xor(m0, off), __shfl_xor(s0, off));
        osm_comb(m1, s1, __shfl_xor(m1, off), __shfl_xor(s1, off));
        osm_comb(m2, s2, __shfl_xor(m2, off), __shfl_xor(s2, off));
        osm_comb(m3, s3, __shfl_xor(m3, off), __shfl_xor(s3, off));
    }
    __shared__ float sm[4][8];
    int lane = threadIdx.x & 63, w = threadIdx.x >> 6;
    if (lane == 0) {
        sm[w][0]=m0; sm[w][1]=m1; sm[w][2]=m2; sm[w][3]=m3;
        sm[w][4]=s0; sm[w][5]=s1; sm[w][6]=s2; sm[w][7]=s3;
    }
    __syncthreads();
    if (threadIdx.x < 4) {
        int hh = threadIdx.x;
        float m = sm[0][hh], s = sm[0][4 + hh];
        osm_comb(m, s, sm[1][hh], sm[1][4 + hh]);
        osm_comb(m, s, sm[2][hh], sm[2][4 + hh]);
        osm_comb(m, s, sm[3][hh], sm[3][4 + hh]);
        part[blockIdx.x * 8 + hh] = m;
        part[blockIdx.x * 8 + 4 + hh] = s;
    }
}

__global__ __launch_bounds__(256) void stat_fin(const float* __restrict__ part,
                                                float* __restrict__ finals)
{
    float m0=-1e30f,m1=-1e30f,m2=-1e30f,m3=-1e30f;
    float s0=0.f,s1=0.f,s2=0.f,s3=0.f;
    for (int r = threadIdx.x; r < RED_BLOCKS; r += 256) {
        osm_comb(m0, s0, part[r*8+0], part[r*8+4]);
        osm_comb(m1, s1, part[r*8+1], part[r*8+5]);
        osm_comb(m2, s2, part[r*8+2], part[r*8+6]);
        osm_comb(m3, s3, part[r*8+3], part[r*8+7]);
    }
#pragma unroll
    for (int off = 32; off >= 1; off >>= 1) {
        osm_comb(m0, s0, __shfl_xor(m0, off), __shfl_xor(s0, off));
        osm_comb(m1, s1, __shfl_xor(m1, off), __shfl_xor(s1, off));
        osm_comb(m2, s2, __shfl_xor(m2, off), __shfl_xor(s2, off));
        osm_comb(m3, s3, __shfl_xor(m3, off), __shfl_xor(s3, off));
    }
    __shared__ float sm[4][8];
    int lane = threadIdx.x & 63, w = threadIdx.x >> 6;
    if (lane == 0) {
        sm[w][0]=m0; sm[w][1]=m1; sm[w][2]=m2; sm[w][3]=m3;
        sm[w][4]=s0; sm[w][5]=s1; sm[w][6]=s2; sm[w][7]=s3;
    }
    __syncthreads();
    if (threadIdx.x < 4) {
        int hh = threadIdx.x;
        float m = sm[0][hh], s = sm[0][4 + hh];
        osm_comb(m, s, sm[1][hh], sm[1][4 + hh]);
        osm_comb(m, s, sm[2][hh], sm[2][4 + hh]);
        osm_comb(m, s, sm[3][hh], sm[3][4 + hh]);
        finals[hh] = m;
        finals[4 + hh] = 1.0f / s;
    }
}

// ---------------------------------------------------------------------------
// CSR build: count -> scan -> fill (sorted by dst)
// ---------------------------------------------------------------------------
__global__ __launch_bounds__(256) void csr_count(
    const void* __restrict__ eia, const void* __restrict__ eib, int split,
    const unsigned* __restrict__ flags, int* __restrict__ cnt)
{
    const bool i64 = (flags[0] != 0u);
    long long e = (long long)blockIdx.x * 256 + threadIdx.x;
    int d = split ? ld_idx(eib, e, i64) : ld_idx(eia, NE + e, i64);
    atomicAdd(&cnt[d], 1);
}

__global__ __launch_bounds__(1024) void csr_scan(const int* __restrict__ cnt,
                                                 int* __restrict__ rowptr,
                                                 int* __restrict__ cursor)
{
    constexpr int T = 1024;
    constexpr int PER = (NN + T - 1) / T; // 49
    __shared__ int psum[T];
    int t = threadIdx.x;
    int base = t * PER;
    int local = 0;
    for (int j = 0; j < PER; ++j) {
        int idx = base + j;
        if (idx < NN) local += cnt[idx];
    }
    psum[t] = local;
    __syncthreads();
    for (int off = 1; off < T; off <<= 1) {
        int v = (t >= off) ? psum[t - off] : 0;
        __syncthreads();
        psum[t] += v;
        __syncthreads();
    }
    int run = (t == 0) ? 0 : psum[t - 1];
    for (int j = 0; j < PER; ++j) {
        int idx = base + j;
        if (idx < NN) {
            rowptr[idx] = run;
            cursor[idx] = run;
            run += cnt[idx];
        }
    }
    if (t == T - 1) rowptr[NN] = run;
}

__global__ __launch_bounds__(256) void csr_fill(
    const void* __restrict__ eia, const void* __restrict__ eib, int split,
    const unsigned* __restrict__ flags,
    int* __restrict__ cursor, int2* __restrict__ se)
{
    const bool i64 = (flags[0] != 0u);
    long long e = (long long)blockIdx.x * 256 + threadIdx.x;
    int s = ld_idx(eia, e, i64);
    int d = split ? ld_idx(eib, e, i64) : ld_idx(eia, NE + e, i64);
    int pos = atomicAdd(&cursor[d], 1);
    se[pos] = make_int2(s, (int)e);
}

// ---------------------------------------------------------------------------
// Kernel 7: atomic-free gather over fp8 v -> bf16 agg. One wave per dst node.
// ---------------------------------------------------------------------------
__global__ __launch_bounds__(256) void gather(
    const int* __restrict__ rowptr, const int2* __restrict__ se,
    const float* __restrict__ logits, const float* __restrict__ finals,
    const unsigned char* __restrict__ vf8, bf16* __restrict__ aggb)
{
    int node = blockIdx.x * 4 + (threadIdx.x >> 6);
    int lane = threadIdx.x & 63;
    int h = lane >> 4;
    float mx = finals[h], inv = finals[4 + h];
    int beg = rowptr[node], end = rowptr[node + 1];
    float o0 = 0.f, o1 = 0.f;
    for (int p = beg; p < end; ++p) {
        int2 q = se[p];
        float lg = logits[(size_t)q.y * NH + h];
        float coef = __expf(lg - mx) * inv;
        unsigned uv = *(const unsigned short*)(vf8 + (size_t)q.x * OC + 2 * lane);
        float v0, v1;
        fp8x2_to_f32(uv, v0, v1);
        o0 = fmaf(coef, v0, o0);
        o1 = fmaf(coef, v1, o1);
    }
    *(unsigned*)(aggb + (size_t)node * OC + 2 * lane) = f2bu(o0) | (f2bu(o1) << 16);
}

// ---------------------------------------------------------------------------
// Kernel 8: MFMA out GEMM + fused LN.
// ---------------------------------------------------------------------------
__global__ __launch_bounds__(256) void out_gemm(
    const bf16* __restrict__ aggb, const bf16* __restrict__ WoT,
    const void* __restrict__ bo, const void* __restrict__ gamma,
    const void* __restrict__ beta, const unsigned* __restrict__ gw,
    void* __restrict__ out)
{
    const bool f32 = (gw[0] == F32_ONE);
    int wave = threadIdx.x >> 6;
    int lane = threadIdx.x & 63;
    int quad = lane >> 4;
    int l16  = lane & 15;
    int rb = blockIdx.x * 64 + wave * 16;
    int m = rb + l16;
    int ma = (m < NN) ? m : 0;

    short8 a[4];
#pragma unroll
    for (int h = 0; h < 4; ++h)
        a[h] = *(const short8*)(aggb + (size_t)ma * OC + h * 32 + quad * 8);

    float o[8][4];
#pragma unroll
    for (int t = 0; t < 8; ++t) {
        const bf16* bp = WoT + (size_t)(t * 16 + l16) * OC + quad * 8;
        f32x4 acc = {0.f, 0.f, 0.f, 0.f};
#pragma unroll
        for (int h = 0; h < 4; ++h) {
            short8 bfr = *(const short8*)(bp + h * 32);
            acc = __builtin_amdgcn_mfma_f32_16x16x32_bf16(a[h], bfr, acc, 0, 0, 0);
        }
        float bias = ldf(bo, t * 16 + l16, f32);
#pragma unroll
        for (int r = 0; r < 4; ++r) o[t][r] = acc[r] + bias;
    }

#pragma unroll
    for (int r = 0; r < 4; ++r) {
        float s1 = 0.f, s2 = 0.f;
#pragma unroll
        for (int t = 0; t < 8; ++t) { s1 += o[t][r]; s2 += o[t][r] * o[t][r]; }
#pragma unroll
        for (int off = 1; off <= 8; off <<= 1) {
            s1 += __shfl_xor(s1, off);
            s2 += __shfl_xor(s2, off);
        }
        float mu = s1 * (1.0f / OC);
        float var = fmaxf(s2 * (1.0f / OC) - mu * mu, 0.f);
        float rs = rsqrtf(var + 1e-5f);
        int node = rb + quad * 4 + r;
        if (node < NN) {
#pragma unroll
            for (int t = 0; t < 8; ++t) {
                int col = t * 16 + l16;
                float y = (o[t][r] - mu) * rs * ldf(gamma, col, f32) + ldf(beta, col, f32);
                if (f32) ((float*)out)[(size_t)node * OC + col] = y;
                else     ((bf16*)out)[(size_t)node * OC + col] = __float2bfloat16(y);
            }
        }
    }
}

// ---------------------------------------------------------------------------
extern "C" void kernel_launch(void* const* d_in, const int* in_sizes, int n_in,
                              void* d_out, int out_size, void* d_ws, size_t ws_size,
                              hipStream_t stream)
{
    int p = 0;
    const void* x   = d_in[p++];
    const void* eia = d_in[p++];
    const void* eib = eia;
    int split = 0;
    if (n_in >= 17) { eib = d_in[p++]; split = 1; }
    const void* Wq   = d_in[p++];
    const void* bq   = d_in[p++];
    const void* Wk   = d_in[p++];
    const void* bk   = d_in[p++];
    const void* Wv   = d_in[p++];
    const void* bv   = d_in[p++];
    const void* We1  = d_in[p++];
    const void* be1  = d_in[p++];
    const void* We2  = d_in[p++];
    const void* be2  = d_in[p++];
    const void* Wo   = d_in[p++];
    const void* bo   = d_in[p++];
    const void* gamma= d_in[p++];
    const void* beta = d_in[p++];
    const unsigned* gw = (const unsigned*)gamma;

    // workspace layout (~45.5 MB):
    char* w = (char*)d_ws;
    float* logits = (float*)w;              w += (size_t)NE * NH * 4;  // 12.8 MB
    unsigned char* qb_dst = (unsigned char*)w; w += (size_t)NN * 256;  // 12.8 MB
    unsigned char* ka_src = (unsigned char*)w; w += (size_t)NN * 256;  // 12.8 MB
    unsigned char* vf8    = (unsigned char*)w; w += (size_t)NN * OC;   // 6.4 MB
    float* part   = (float*)w;              w += (size_t)RED_BLOCKS * 8 * 4;
    float* finals = (float*)w;              w += 8 * 4;
    unsigned* flags = (unsigned*)w;         w += 16;
    float* be1f   = (float*)w;              w += OC * 4;
    float* We2f   = (float*)w;              w += OC * NH * 4;
    float* be2f   = (float*)w;              w += NH * 4;
    bf16*  WcatT  = (bf16*)w;               w += (size_t)5 * OC * IC * 2; // 160 KB
    float* bcat   = (float*)w;              w += 5 * OC * 4;
    bf16*  WoT    = (bf16*)w;               w += (size_t)OC * OC * 2;     // 32 KB

    // aliases (regions dead at time of reuse):
    bf16*  xb     = (bf16*)logits;          // 6.4 MB over logits (pre-edge)
    bf16*  aggb   = (bf16*)qb_dst;          // 12.8 MB over qb_dst (post-edge)
    int*   cnt    = (int*)ka_src;           // 600 KB over ka_src (post-edge)
    int*   rowptr = cnt + NN;
    int*   cursor = rowptr + NN + 1;
    int2*  se     = (int2*)(ka_src + 1024 * 1024); // 6.4 MB, also in ka_src region
    // (cnt+rowptr+cursor = ~600 KB < 1 MB offset; se 6.4 MB; total < 12.8 MB) ✓

    if (ws_size < (size_t)((char*)w - (char*)d_ws)) return;

    probe_idx<<<1, 64, 0, stream>>>((const unsigned*)eia, flags);
    cvt_small<<<1, 256, 0, stream>>>(be1, We2, be2, gw, bq, bk, bv,
                                     be1f, We2f, be2f, bcat);
    cvt_x<<<(NN * IC + 255) / 256, 256, 0, stream>>>(x, gw, xb);
    cvt_w<<<(5 * OC * IC + 255) / 256, 256, 0, stream>>>(Wq, Wk, Wv, We1, gw, WcatT);
    cvt_wo<<<(OC * OC + 255) / 256, 256, 0, stream>>>(Wo, gw, WoT);
    node_gemm<<<NN / 16, 256, 0, stream>>>(xb, WcatT, bcat, qb_dst, ka_src, vf8);
    edge_kernel<<<NE / 8, 256, 0, stream>>>(eia, eib, split, flags,
                                            qb_dst, ka_src, be1f, We2f, be2f, logits);
    // CSR build (qb_dst/ka_src table contents dead after edge_kernel)
    hipMemsetAsync(cnt, 0, (size_t)NN * 4, stream);
    csr_count<<<NE / 256, 256, 0, stream>>>(eia, eib, split, flags, cnt);
    csr_scan<<<1, 1024, 0, stream>>>(cnt, rowptr, cursor);
    csr_fill<<<NE / 256, 256, 0, stream>>>(eia, eib, split, flags, cursor, se);
    // fused online-softmax stats (one pass)
    stat_part<<<RED_BLOCKS, 256, 0, stream>>>(logits, part);
    stat_fin<<<1, 256, 0, stream>>>(part, finals);
    // aggregation then fused GEMM+LN
    gather<<<NN / 4, 256, 0, stream>>>(rowptr, se, logits, finals, vf8, aggb);
    out_gemm<<<(NN + 63) / 64, 256, 0, stream>>>(aggb, WoT, bo, gamma, beta, gw, d_out);
}

// Round 10
// 620.685 us; speedup vs baseline: 1.0302x; 1.0302x over previous
//
#include <hip/hip_runtime.h>
#include <hip/hip_bf16.h>

typedef __hip_bfloat16 bf16;
typedef __attribute__((ext_vector_type(8))) short short8;   // 8 bf16 (4 VGPRs)
typedef __attribute__((ext_vector_type(4))) float f32x4;    // 4 fp32 acc
typedef __attribute__((ext_vector_type(2))) float f32x2;

constexpr int NN = 50000;   // nodes
constexpr int NE = 800000;  // edges
constexpr int IC = 64;      // in channels
constexpr int OC = 128;     // out channels
constexpr int NH = 4;       // heads
constexpr int RED_BLOCKS = 512;
constexpr unsigned F32_ONE = 0x3F800000u;

__device__ __forceinline__ float ldf(const void* p, int i, bool f32) {
    return f32 ? ((const float*)p)[i]
               : __bfloat162float(((const bf16*)p)[i]);
}

__device__ __forceinline__ int ld_idx(const void* p, long long i, bool i64) {
    return i64 ? (int)((const long long*)p)[i] : ((const int*)p)[i];
}

// inline edge-index width probe: int64 node indices (<2^31) have zero high words
__device__ __forceinline__ bool probe_i64(const void* ei) {
    const unsigned* u = (const unsigned*)ei;
    return (u[1] | u[3] | u[5] | u[7]) == 0u;
}

// f32 -> bf16 bits (RNE)
__device__ __forceinline__ unsigned f2bu(float x) {
    unsigned u = __float_as_uint(x);
    return (u + 0x7FFFu + ((u >> 16) & 1u)) >> 16;
}

// ---- fp8 e4m3 helpers (HW path with manual fallback) ----------------------
__device__ __forceinline__ unsigned char f32_to_fp8(float x) {
#if __has_builtin(__builtin_amdgcn_cvt_pk_fp8_f32)
    return (unsigned char)(__builtin_amdgcn_cvt_pk_fp8_f32(x, x, 0, false) & 0xFF);
#else
    unsigned bits = __float_as_uint(x);
    unsigned s = bits >> 31;
    float a = fabsf(x);
    if (a >= 448.f) return (unsigned char)((s << 7) | 0x7E);
    if (a < 0.015625f) {
        int m = (int)(a * 512.f + 0.5f);
        if (m >= 8) return (unsigned char)((s << 7) | 0x08);
        return (unsigned char)((s << 7) | m);
    }
    unsigned ab = (bits & 0x7FFFFFFFu) + 0x00080000u;
    int e8 = (int)(ab >> 23) - 127 + 7;
    unsigned m3 = (ab >> 20) & 7u;
    if (e8 >= 16) return (unsigned char)((s << 7) | 0x7E);
    return (unsigned char)((s << 7) | ((unsigned)e8 << 3) | m3);
#endif
}

__device__ __forceinline__ void fp8x4_to_f32(unsigned u, float& f0, float& f1,
                                             float& f2, float& f3) {
#if __has_builtin(__builtin_amdgcn_cvt_pk_f32_fp8)
    f32x2 lo = __builtin_amdgcn_cvt_pk_f32_fp8(u, false);
    f32x2 hi = __builtin_amdgcn_cvt_pk_f32_fp8(u, true);
    f0 = lo[0]; f1 = lo[1]; f2 = hi[0]; f3 = hi[1];
#else
    float r[4];
#pragma unroll
    for (int j = 0; j < 4; ++j) {
        unsigned b = (u >> (8 * j)) & 0xFF;
        unsigned s = b >> 7, e = (b >> 3) & 15, m = b & 7;
        float v = (e == 0) ? (float)m * 0.001953125f
                           : __uint_as_float(((e + 120u) << 23) | (m << 20));
        r[j] = s ? -v : v;
    }
    f0 = r[0]; f1 = r[1]; f2 = r[2]; f3 = r[3];
#endif
}

__device__ __forceinline__ void fp8x2_to_f32(unsigned u, float& f0, float& f1) {
#if __has_builtin(__builtin_amdgcn_cvt_pk_f32_fp8)
    f32x2 lo = __builtin_amdgcn_cvt_pk_f32_fp8(u, false);
    f0 = lo[0]; f1 = lo[1];
#else
    float r[2];
#pragma unroll
    for (int j = 0; j < 2; ++j) {
        unsigned b = (u >> (8 * j)) & 0xFF;
        unsigned s = b >> 7, e = (b >> 3) & 15, m = b & 7;
        float v = (e == 0) ? (float)m * 0.001953125f
                           : __uint_as_float(((e + 120u) << 23) | (m << 20));
        r[j] = s ? -v : v;
    }
    f0 = r[0]; f1 = r[1];
#endif
}

// online-softmax combine
__device__ __forceinline__ void osm_comb(float& m, float& s, float m2, float s2) {
    float M = fmaxf(m, m2);
    s = s * __expf(m - M) + s2 * __expf(m2 - M);
    m = M;
}

// ---------------------------------------------------------------------------
// prep: fused one-shot conversions + cnt zeroing.
// blocks [0,12500): x->bf16 | [12500,12660): WcatT | [12660,12724): WoT
// [12724,12920): zero cnt | 12920: small tables
// ---------------------------------------------------------------------------
constexpr int PB_X  = 12500;
constexpr int PB_W  = 160;
constexpr int PB_WO = 64;
constexpr int PB_C  = 196;

__global__ __launch_bounds__(256) void prep(
    const void* __restrict__ x,
    const void* __restrict__ Wq, const void* __restrict__ bq,
    const void* __restrict__ Wk, const void* __restrict__ bk,
    const void* __restrict__ Wv, const void* __restrict__ bv,
    const void* __restrict__ We1, const void* __restrict__ be1,
    const void* __restrict__ We2, const void* __restrict__ be2,
    const void* __restrict__ Wo,  const unsigned* __restrict__ gw,
    bf16* __restrict__ xb, bf16* __restrict__ WcatT, bf16* __restrict__ WoT,
    int* __restrict__ cnt,
    float* __restrict__ be1f, float* __restrict__ We2f, float* __restrict__ be2f,
    float* __restrict__ bcat)
{
    const bool f32 = (gw[0] == F32_ONE);
    int b = blockIdx.x, t = threadIdx.x;
    if (b < PB_X) {
        int i = b * 256 + t;
        if (i < NN * IC) xb[i] = __float2bfloat16(ldf(x, i, f32));
    } else if (b < PB_X + PB_W) {
        int idx = (b - PB_X) * 256 + t;         // n*64 + k
        int n = idx >> 6, k = idx & 63;
        int sel = n >> 7, c = n & 127;
        float v;
        if (sel == 0)      v = ldf(Wq, k * OC + c, f32);
        else if (sel == 1) v = ldf(Wk, k * OC + c, f32);
        else if (sel == 2) v = ldf(Wv, k * OC + c, f32);
        else if (sel == 3) v = ldf(We1, k * OC + c, f32);
        else               v = ldf(We1, (IC + k) * OC + c, f32);
        WcatT[idx] = __float2bfloat16(v);
    } else if (b < PB_X + PB_W + PB_WO) {
        int idx = (b - PB_X - PB_W) * 256 + t;  // n*128 + k
        int n = idx >> 7, k = idx & 127;
        WoT[idx] = __float2bfloat16(ldf(Wo, k * OC + n, f32));
    } else if (b < PB_X + PB_W + PB_WO + PB_C) {
        int i = (b - PB_X - PB_W - PB_WO) * 256 + t;
        if (i < NN) cnt[i] = 0;
    } else {
        if (t < OC) be1f[t] = ldf(be1, t, f32);
        for (int i = t; i < OC * NH; i += 256) We2f[i] = ldf(We2, i, f32);
        if (t < NH) be2f[t] = ldf(be2, t, f32);
        for (int n = t; n < 5 * OC; n += 256) {
            int sel = n >> 7, c = n & 127;
            float bb = 0.f;
            if (sel == 0) bb = ldf(bq, c, f32);
            else if (sel == 1) bb = ldf(bk, c, f32);
            else if (sel == 2) bb = ldf(bv, c, f32);
            bcat[n] = bb;
        }
    }
}

// ---------------------------------------------------------------------------
// CSR build: count -> scan -> fill (sorted by dst). ssrc[pos] = src node.
// ---------------------------------------------------------------------------
__global__ __launch_bounds__(256) void csr_count(
    const void* __restrict__ eia, const void* __restrict__ eib, int split,
    int* __restrict__ cnt)
{
    const bool i64 = probe_i64(eia);
    long long e = (long long)blockIdx.x * 256 + threadIdx.x;
    int d = split ? ld_idx(eib, e, i64) : ld_idx(eia, NE + e, i64);
    atomicAdd(&cnt[d], 1);
}

__global__ __launch_bounds__(1024) void csr_scan(const int* __restrict__ cnt,
                                                 int* __restrict__ rowptr,
                                                 int* __restrict__ cursor)
{
    constexpr int T = 1024;
    constexpr int PER = (NN + T - 1) / T;
    __shared__ int psum[T];
    int t = threadIdx.x;
    int base = t * PER;
    int local = 0;
    for (int j = 0; j < PER; ++j) {
        int idx = base + j;
        if (idx < NN) local += cnt[idx];
    }
    psum[t] = local;
    __syncthreads();
    for (int off = 1; off < T; off <<= 1) {
        int v = (t >= off) ? psum[t - off] : 0;
        __syncthreads();
        psum[t] += v;
        __syncthreads();
    }
    int run = (t == 0) ? 0 : psum[t - 1];
    for (int j = 0; j < PER; ++j) {
        int idx = base + j;
        if (idx < NN) {
            rowptr[idx] = run;
            cursor[idx] = run;
            run += cnt[idx];
        }
    }
    if (t == T - 1) rowptr[NN] = run;
}

__global__ __launch_bounds__(256) void csr_fill(
    const void* __restrict__ eia, const void* __restrict__ eib, int split,
    int* __restrict__ cursor, int* __restrict__ ssrc)
{
    const bool i64 = probe_i64(eia);
    long long e = (long long)blockIdx.x * 256 + threadIdx.x;
    int s = ld_idx(eia, e, i64);
    int d = split ? ld_idx(eib, e, i64) : ld_idx(eia, NE + e, i64);
    int pos = atomicAdd(&cursor[d], 1);
    ssrc[pos] = s;
}

// ---------------------------------------------------------------------------
// node_gemm: D[50000 x 640] = xb @ Wcat + bcat  (MFMA 16x16x32 bf16)
// fp8 outputs: qb_dst row = [q 128B | b 128B], ka_src row = [k 128B | a 128B],
// vf8 row = 128B.
// ---------------------------------------------------------------------------
__global__ __launch_bounds__(256) void node_gemm(
    const bf16* __restrict__ xb, const bf16* __restrict__ WcatT,
    const float* __restrict__ bcat,
    unsigned char* __restrict__ qb_dst, unsigned char* __restrict__ ka_src,
    unsigned char* __restrict__ vf8)
{
    int wave = threadIdx.x >> 6;
    int lane = threadIdx.x & 63;
    int quad = lane >> 4;
    int l16  = lane & 15;
    int row_base = blockIdx.x * 16;
    int m = row_base + l16;

    short8 a0 = *(const short8*)(xb + (size_t)m * IC + quad * 8);
    short8 a1 = *(const short8*)(xb + (size_t)m * IC + 32 + quad * 8);

#pragma unroll
    for (int t = 0; t < 10; ++t) {
        int colbase = wave * 160 + t * 16;
        const bf16* bp = WcatT + (size_t)(colbase + l16) * IC + quad * 8;
        short8 b0 = *(const short8*)(bp);
        short8 b1 = *(const short8*)(bp + 32);
        f32x4 acc = {0.f, 0.f, 0.f, 0.f};
        acc = __builtin_amdgcn_mfma_f32_16x16x32_bf16(a0, b0, acc, 0, 0, 0);
        acc = __builtin_amdgcn_mfma_f32_16x16x32_bf16(a1, b1, acc, 0, 0, 0);

        float bias = bcat[colbase + l16];
        int sel = colbase >> 7;
        int cc  = (colbase & 127) + l16;
#pragma unroll
        for (int r = 0; r < 4; ++r) {
            int node = row_base + quad * 4 + r;
            unsigned char val = f32_to_fp8(acc[r] + bias);
            if (sel == 0)      qb_dst[(size_t)node * 256 + cc] = val;
            else if (sel == 1) ka_src[(size_t)node * 256 + cc] = val;
            else if (sel == 2) vf8[(size_t)node * OC + cc] = val;
            else if (sel == 3) ka_src[(size_t)node * 256 + 128 + cc] = val;
            else               qb_dst[(size_t)node * 256 + 128 + cc] = val;
        }
    }
}

// ---------------------------------------------------------------------------
// edge_csr: one wave per dst node. dst row (q|b) loaded once; loop over
// in-edges gathers src row (k|a), computes logit, writes at CSR position
// (logits end up in CSR order). Lanes 0-31: q/k (dot); lanes 32-63: b/a (gate).
// 2-deep src-row prefetch.
// ---------------------------------------------------------------------------
__global__ __launch_bounds__(256) void edge_csr(
    const int* __restrict__ rowptr, const int* __restrict__ ssrc,
    const unsigned char* __restrict__ qb_dst, const unsigned char* __restrict__ ka_src,
    const float* __restrict__ be1f, const float* __restrict__ We2f,
    const float* __restrict__ be2f,
    float* __restrict__ logits)
{
    int node = blockIdx.x * 4 + (threadIdx.x >> 6);
    int lane = threadIdx.x & 63;
    int li   = lane & 31;
    int c    = li << 2;
    int j    = li & 3;

    // dst row once: lane<32 -> q chunk, lane>=32 -> b chunk
    unsigned drow = *(const unsigned*)(qb_dst + (size_t)node * 256 + lane * 4);
    float d0, d1, d2, d3;
    fp8x4_to_f32(drow, d0, d1, d2, d3);

    float4 vb1 = *(const float4*)(be1f + c);
    float4 w0 = *(const float4*)(We2f + 4 * c);
    float4 w1 = *(const float4*)(We2f + 4 * (c + 1));
    float4 w2 = *(const float4*)(We2f + 4 * (c + 2));
    float4 w3 = *(const float4*)(We2f + 4 * (c + 3));
    float be2j = be2f[j];

    int beg = rowptr[node], end = rowptr[node + 1];
    if (beg >= end) return;  // wave-uniform

    int s0i = ssrc[beg];
    unsigned srow_n = *(const unsigned*)(ka_src + (size_t)s0i * 256 + lane * 4);

    for (int p = beg; p < end; ++p) {
        unsigned srow = srow_n;
        if (p + 1 < end) {
            int s2 = ssrc[p + 1];
            srow_n = *(const unsigned*)(ka_src + (size_t)s2 * 256 + lane * 4);
        }
        float s0, s1, s2f, s3;
        fp8x4_to_f32(srow, s0, s1, s2f, s3);

        // dot (lower half: d=q, s=k); garbage on upper half, unused
        float t = d0 * s0 + d1 * s1 + d2 * s2f + d3 * s3;
        t += __shfl_xor(t, 1);
        t += __shfl_xor(t, 2);
        t += __shfl_xor(t, 4);        // lanes 8h..8h+7 hold t_h (lower half)

        // gate (upper half: d=b, s=a)
        float h0 = fmaxf(s0 + d0 + vb1.x, 0.f);
        float h1 = fmaxf(s1 + d1 + vb1.y, 0.f);
        float h2 = fmaxf(s2f + d2 + vb1.z, 0.f);
        float h3 = fmaxf(s3 + d3 + vb1.w, 0.f);
        float p0 = h0 * w0.x + h1 * w1.x + h2 * w2.x + h3 * w3.x;
        float p1 = h0 * w0.y + h1 * w1.y + h2 * w2.y + h3 * w3.y;
        float p2 = h0 * w0.z + h1 * w1.z + h2 * w2.z + h3 * w3.z;
        float p3 = h0 * w0.w + h1 * w1.w + h2 * w2.w + h3 * w3.w;
        // 2 stages on 4 values
        p0 += __shfl_xor(p0, 1); p1 += __shfl_xor(p1, 1);
        p2 += __shfl_xor(p2, 1); p3 += __shfl_xor(p3, 1);
        p0 += __shfl_xor(p0, 2); p1 += __shfl_xor(p1, 2);
        p2 += __shfl_xor(p2, 2); p3 += __shfl_xor(p3, 2);
        // select own head, 3 stages on single value
        float pj = (j == 0) ? p0 : (j == 1) ? p1 : (j == 2) ? p2 : p3;
        pj += __shfl_xor(pj, 4);
        pj += __shfl_xor(pj, 8);
        pj += __shfl_xor(pj, 16);     // full 128-ch sum for head j (within half)

        float tj = __shfl(t, 8 * j);  // t_j from lower-half lane 8j

        if (lane >= 32 && li < 4) {   // lanes 32..35 write j=0..3 (16B coalesced)
            float w = pj + be2j;
            logits[(size_t)p * 4 + j] = tj * w * 0.17677669529663687f; // 1/sqrt(32)
        }
    }
}

// ---------------------------------------------------------------------------
// Fused online-softmax stats: one pass over logits (order-independent).
// ---------------------------------------------------------------------------
__global__ __launch_bounds__(256) void stat_part(const float* __restrict__ logits,
                                                 float* __restrict__ part)
{
    float m0=-1e30f,m1=-1e30f,m2=-1e30f,m3=-1e30f;
    float s0=0.f,s1=0.f,s2=0.f,s3=0.f;
    for (int e = blockIdx.x * 256 + threadIdx.x; e < NE; e += RED_BLOCKS * 256) {
        float4 l = reinterpret_cast<const float4*>(logits)[e];
        float M;
        M = fmaxf(m0, l.x); s0 = s0 * __expf(m0 - M) + __expf(l.x - M); m0 = M;
        M = fmaxf(m1, l.y); s1 = s1 * __expf(m1 - M) + __expf(l.y - M); m1 = M;
        M = fmaxf(m2, l.z); s2 = s2 * __expf(m2 - M) + __expf(l.z - M); m2 = M;
        M = fmaxf(m3, l.w); s3 = s3 * __expf(m3 - M) + __expf(l.w - M); m3 = M;
    }
#pragma unroll
    for (int off = 32; off >= 1; off >>= 1) {
        osm_comb(m0, s0, __shfl_xor(m0, off), __shfl_xor(s0, off));
        osm_comb(m1, s1, __shfl_xor(m1, off), __shfl_xor(s1, off));
        osm_comb(m2, s2, __shfl_xor(m2, off), __shfl_xor(s2, off));
        osm_comb(m3, s3, __shfl_xor(m3, off), __shfl_xor(s3, off));
    }
    __shared__ float sm[4][8];
    int lane = threadIdx.x & 63, w = threadIdx.x >> 6;
    if (lane == 0) {
        sm[w][0]=m0; sm[w][1]=m1; sm[w][2]=m2; sm[w][3]=m3;
        sm[w][4]=s0; sm[w][5]=s1; sm[w][6]=s2; sm[w][7]=s3;
    }
    __syncthreads();
    if (threadIdx.x < 4) {
        int hh = threadIdx.x;
        float m = sm[0][hh], s = sm[0][4 + hh];
        osm_comb(m, s, sm[1][hh], sm[1][4 + hh]);
        osm_comb(m, s, sm[2][hh], sm[2][4 + hh]);
        osm_comb(m, s, sm[3][hh], sm[3][4 + hh]);
        part[blockIdx.x * 8 + hh] = m;
        part[blockIdx.x * 8 + 4 + hh] = s;
    }
}

__global__ __launch_bounds__(256) void stat_fin(const float* __restrict__ part,
                                                float* __restrict__ finals)
{
    float m0=-1e30f,m1=-1e30f,m2=-1e30f,m3=-1e30f;
    float s0=0.f,s1=0.f,s2=0.f,s3=0.f;
    for (int r = threadIdx.x; r < RED_BLOCKS; r += 256) {
        osm_comb(m0, s0, part[r*8+0], part[r*8+4]);
        osm_comb(m1, s1, part[r*8+1], part[r*8+5]);
        osm_comb(m2, s2, part[r*8+2], part[r*8+6]);
        osm_comb(m3, s3, part[r*8+3], part[r*8+7]);
    }
#pragma unroll
    for (int off = 32; off >= 1; off >>= 1) {
        osm_comb(m0, s0, __shfl_xor(m0, off), __shfl_xor(s0, off));
        osm_comb(m1, s1, __shfl_xor(m1, off), __shfl_xor(s1, off));
        osm_comb(m2, s2, __shfl_xor(m2, off), __shfl_xor(s2, off));
        osm_comb(m3, s3, __shfl_xor(m3, off), __shfl_xor(s3, off));
    }
    __shared__ float sm[4][8];
    int lane = threadIdx.x & 63, w = threadIdx.x >> 6;
    if (lane == 0) {
        sm[w][0]=m0; sm[w][1]=m1; sm[w][2]=m2; sm[w][3]=m3;
        sm[w][4]=s0; sm[w][5]=s1; sm[w][6]=s2; sm[w][7]=s3;
    }
    __syncthreads();
    if (threadIdx.x < 4) {
        int hh = threadIdx.x;
        float m = sm[0][hh], s = sm[0][4 + hh];
        osm_comb(m, s, sm[1][hh], sm[1][4 + hh]);
        osm_comb(m, s, sm[2][hh], sm[2][4 + hh]);
        osm_comb(m, s, sm[3][hh], sm[3][4 + hh]);
        finals[hh] = m;
        finals[4 + hh] = 1.0f / s;
    }
}

// ---------------------------------------------------------------------------
// gather: one wave per dst node; sequential logits (CSR order), random vf8
// rows with 2-deep prefetch. Writes bf16 agg row once.
// ---------------------------------------------------------------------------
__global__ __launch_bounds__(256) void gather(
    const int* __restrict__ rowptr, const int* __restrict__ ssrc,
    const float* __restrict__ logits, const float* __restrict__ finals,
    const unsigned char* __restrict__ vf8, bf16* __restrict__ aggb)
{
    int node = blockIdx.x * 4 + (threadIdx.x >> 6);
    int lane = threadIdx.x & 63;
    int h = lane >> 4;
    float mx = finals[h], inv = finals[4 + h];
    int beg = rowptr[node], end = rowptr[node + 1];
    float o0 = 0.f, o1 = 0.f;

    if (beg < end) {
        int sfirst = ssrc[beg];
        unsigned uv_n = *(const unsigned short*)(vf8 + (size_t)sfirst * OC + 2 * lane);
        for (int p = beg; p < end; ++p) {
            unsigned uv = uv_n;
            if (p + 1 < end) {
                int s2 = ssrc[p + 1];
                uv_n = *(const unsigned short*)(vf8 + (size_t)s2 * OC + 2 * lane);
            }
            float lg = logits[(size_t)p * 4 + h];       // sequential line
            float coef = __expf(lg - mx) * inv;
            float v0, v1;
            fp8x2_to_f32(uv, v0, v1);
            o0 = fmaf(coef, v0, o0);
            o1 = fmaf(coef, v1, o1);
        }
    }
    *(unsigned*)(aggb + (size_t)node * OC + 2 * lane) = f2bu(o0) | (f2bu(o1) << 16);
}

// ---------------------------------------------------------------------------
// out_gemm: MFMA out GEMM + fused LN.
// ---------------------------------------------------------------------------
__global__ __launch_bounds__(256) void out_gemm(
    const bf16* __restrict__ aggb, const bf16* __restrict__ WoT,
    const void* __restrict__ bo, const void* __restrict__ gamma,
    const void* __restrict__ beta, const unsigned* __restrict__ gw,
    void* __restrict__ out)
{
    const bool f32 = (gw[0] == F32_ONE);
    int wave = threadIdx.x >> 6;
    int lane = threadIdx.x & 63;
    int quad = lane >> 4;
    int l16  = lane & 15;
    int rb = blockIdx.x * 64 + wave * 16;
    int m = rb + l16;
    int ma = (m < NN) ? m : 0;

    short8 a[4];
#pragma unroll
    for (int h = 0; h < 4; ++h)
        a[h] = *(const short8*)(aggb + (size_t)ma * OC + h * 32 + quad * 8);

    float o[8][4];
#pragma unroll
    for (int t = 0; t < 8; ++t) {
        const bf16* bp = WoT + (size_t)(t * 16 + l16) * OC + quad * 8;
        f32x4 acc = {0.f, 0.f, 0.f, 0.f};
#pragma unroll
        for (int h = 0; h < 4; ++h) {
            short8 bfr = *(const short8*)(bp + h * 32);
            acc = __builtin_amdgcn_mfma_f32_16x16x32_bf16(a[h], bfr, acc, 0, 0, 0);
        }
        float bias = ldf(bo, t * 16 + l16, f32);
#pragma unroll
        for (int r = 0; r < 4; ++r) o[t][r] = acc[r] + bias;
    }

#pragma unroll
    for (int r = 0; r < 4; ++r) {
        float s1 = 0.f, s2 = 0.f;
#pragma unroll
        for (int t = 0; t < 8; ++t) { s1 += o[t][r]; s2 += o[t][r] * o[t][r]; }
#pragma unroll
        for (int off = 1; off <= 8; off <<= 1) {
            s1 += __shfl_xor(s1, off);
            s2 += __shfl_xor(s2, off);
        }
        float mu = s1 * (1.0f / OC);
        float var = fmaxf(s2 * (1.0f / OC) - mu * mu, 0.f);
        float rs = rsqrtf(var + 1e-5f);
        int node = rb + quad * 4 + r;
        if (node < NN) {
#pragma unroll
            for (int t = 0; t < 8; ++t) {
                int col = t * 16 + l16;
                float y = (o[t][r] - mu) * rs * ldf(gamma, col, f32) + ldf(beta, col, f32);
                if (f32) ((float*)out)[(size_t)node * OC + col] = y;
                else     ((bf16*)out)[(size_t)node * OC + col] = __float2bfloat16(y);
            }
        }
    }
}

// ---------------------------------------------------------------------------
extern "C" void kernel_launch(void* const* d_in, const int* in_sizes, int n_in,
                              void* d_out, int out_size, void* d_ws, size_t ws_size,
                              hipStream_t stream)
{
    int p = 0;
    const void* x   = d_in[p++];
    const void* eia = d_in[p++];
    const void* eib = eia;
    int split = 0;
    if (n_in >= 17) { eib = d_in[p++]; split = 1; }
    const void* Wq   = d_in[p++];
    const void* bq   = d_in[p++];
    const void* Wk   = d_in[p++];
    const void* bk   = d_in[p++];
    const void* Wv   = d_in[p++];
    const void* bv   = d_in[p++];
    const void* We1  = d_in[p++];
    const void* be1  = d_in[p++];
    const void* We2  = d_in[p++];
    const void* be2  = d_in[p++];
    const void* Wo   = d_in[p++];
    const void* bo   = d_in[p++];
    const void* gamma= d_in[p++];
    const void* beta = d_in[p++];
    const unsigned* gw = (const unsigned*)gamma;

    // workspace layout (~49 MB):
    char* w = (char*)d_ws;
    float* logits = (float*)w;                 w += (size_t)NE * NH * 4;  // 12.8 MB (CSR order)
    unsigned char* qb_dst = (unsigned char*)w; w += (size_t)NN * 256;     // 12.8 MB
    unsigned char* ka_src = (unsigned char*)w; w += (size_t)NN * 256;     // 12.8 MB
    unsigned char* vf8    = (unsigned char*)w; w += (size_t)NN * OC;      // 6.4 MB
    int*   ssrc   = (int*)w;                   w += (size_t)NE * 4;       // 3.2 MB
    int*   cnt    = (int*)w;                   w += (size_t)NN * 4;
    int*   rowptr = (int*)w;                   w += (size_t)(NN + 1) * 4;
    int*   cursor = (int*)w;                   w += (size_t)NN * 4;
    float* part   = (float*)w;                 w += (size_t)RED_BLOCKS * 8 * 4;
    float* finals = (float*)w;                 w += 8 * 4;
    float* be1f   = (float*)w;                 w += OC * 4;
    float* We2f   = (float*)w;                 w += OC * NH * 4;
    float* be2f   = (float*)w;                 w += NH * 4;
    bf16*  WcatT  = (bf16*)w;                  w += (size_t)5 * OC * IC * 2;
    float* bcat   = (float*)w;                 w += 5 * OC * 4;
    bf16*  WoT    = (bf16*)w;                  w += (size_t)OC * OC * 2;

    // aliases (dead regions at time of reuse):
    bf16*  xb     = (bf16*)logits;   // 6.4 MB over logits (dead before edge_csr writes)
    bf16*  aggb   = (bf16*)qb_dst;   // 12.8 MB over qb_dst (dead after edge_csr)

    if (ws_size < (size_t)((char*)w - (char*)d_ws)) return;

    prep<<<PB_X + PB_W + PB_WO + PB_C + 1, 256, 0, stream>>>(
        x, Wq, bq, Wk, bk, Wv, bv, We1, be1, We2, be2, Wo, gw,
        xb, WcatT, WoT, cnt, be1f, We2f, be2f, bcat);
    csr_count<<<NE / 256, 256, 0, stream>>>(eia, eib, split, cnt);
    csr_scan<<<1, 1024, 0, stream>>>(cnt, rowptr, cursor);
    csr_fill<<<NE / 256, 256, 0, stream>>>(eia, eib, split, cursor, ssrc);
    node_gemm<<<NN / 16, 256, 0, stream>>>(xb, WcatT, bcat, qb_dst, ka_src, vf8);
    edge_csr<<<NN / 4, 256, 0, stream>>>(rowptr, ssrc, qb_dst, ka_src,
                                         be1f, We2f, be2f, logits);
    stat_part<<<RED_BLOCKS, 256, 0, stream>>>(logits, part);
    stat_fin<<<1, 256, 0, stream>>>(part, finals);
    gather<<<NN / 4, 256, 0, stream>>>(rowptr, ssrc, logits, finals, vf8, aggb);
    out_gemm<<<(NN + 63) / 64, 256, 0, stream>>>(aggb, WoT, bo, gamma, beta, gw, d_out);
}